// Round 1
// baseline (99.364 us; speedup 1.0000x reference)
//
#include <hip/hip_runtime.h>

#define NB_     32
#define NSITES_ 65536
#define NNGB_   13
#define DIM_    3
#define NG_     48

// ---------------------------------------------------------------------------
// Kernel 1: compute Wmean[3][13] into d_ws[0..38].
// Wmean[d,j] = (1/48) * sum_k colsum[d,k] * Wp[k,j]
//   colsum[d,k] = sum_g gdiags[g*3+d, k]
//   Wp[g*3+dp, j] = wtVC[dp, GnnPerms[g,j]]
// ---------------------------------------------------------------------------
__global__ __launch_bounds__(256) void wmean_kernel_78486(
    const float* __restrict__ wtVC,     // (3,13)
    const float* __restrict__ gdiags,   // (144,144)
    const int*   __restrict__ perms,    // (48,13)
    float* __restrict__ wm_out)         // 39 floats
{
    __shared__ float wt[DIM_ * NNGB_];          // 39
    __shared__ int   pm[NG_ * NNGB_];           // 624
    __shared__ float wp[NG_ * DIM_ * NNGB_];    // 1872
    __shared__ float cs[DIM_ * NG_ * DIM_];     // 3*144 = 432
    const int t = threadIdx.x;

    for (int e = t; e < DIM_ * NNGB_; e += 256) wt[e] = wtVC[e];
    for (int e = t; e < NG_ * NNGB_; e += 256) pm[e] = perms[e];
    __syncthreads();

    // Build Wp (144 x 13)
    for (int e = t; e < NG_ * DIM_ * NNGB_; e += 256) {
        int k = e / NNGB_, j = e - NNGB_ * k;
        int g = k / DIM_, d = k - DIM_ * g;
        wp[e] = wt[d * NNGB_ + pm[g * NNGB_ + j]];
    }
    // colsum (3 x 144)
    for (int e = t; e < DIM_ * NG_ * DIM_; e += 256) {
        int d = e / 144, k = e - 144 * d;
        float s = 0.f;
        for (int g = 0; g < NG_; g++) s += gdiags[(g * DIM_ + d) * 144 + k];
        cs[e] = s;
    }
    __syncthreads();

    if (t < DIM_ * NNGB_) {
        int d = t / NNGB_, j = t - NNGB_ * d;
        float s = 0.f;
        for (int k = 0; k < 144; k++) s += cs[d * 144 + k] * wp[k * NNGB_ + j];
        wm_out[t] = s * (1.0f / NG_);
    }
}

// ---------------------------------------------------------------------------
// Kernel 2: transpose In (32, 65536) -> InT (65536, 32)
// One block handles 64 sites x 32 batches via a padded LDS tile.
// ---------------------------------------------------------------------------
__global__ __launch_bounds__(256) void transpose_kernel_78486(
    const float* __restrict__ In, float* __restrict__ InT)
{
    __shared__ float tile[NB_][65];   // [b][site-local], padded
    const int s0 = blockIdx.x * 64;
    const int t  = threadIdx.x;

    const int sl = t & 63;
    const int bq = t >> 6;            // 0..3
#pragma unroll
    for (int r = 0; r < 8; r++) {
        int b = bq * 8 + r;
        tile[b][sl] = In[b * NSITES_ + s0 + sl];
    }
    __syncthreads();

    const int li = t & 31;            // batch lane
    const int gi = t >> 5;            // 0..7
#pragma unroll
    for (int w = 0; w < 8; w++) {
        int sl2 = gi * 8 + w;         // 0..63
        InT[(s0 + sl2) * NB_ + li] = tile[li][sl2];
    }
}

// ---------------------------------------------------------------------------
// Kernel 3: main gather-conv.
// thread = (site, batch-quarter). 4 consecutive lanes cover one site's
// 128-B InT row. acc[3][8] per thread.
// out[b,d,s] = sum_j wm[d*13+j] * InT[nn[j,s]*32 + b]
// ---------------------------------------------------------------------------
__global__ __launch_bounds__(256) void gather_kernel_78486(
    const float* __restrict__ InT,
    const int*   __restrict__ nn,     // (13, 65536)
    const float* __restrict__ wm,     // 39
    float* __restrict__ out)          // (32, 3, 65536)
{
    const int t = blockIdx.x * 256 + threadIdx.x;   // 0..262143
    const int q = t & 3;                            // batch quarter
    const int s = t >> 2;                           // site

    __shared__ float ws[DIM_ * NNGB_];
    if (threadIdx.x < DIM_ * NNGB_) ws[threadIdx.x] = wm[threadIdx.x];
    __syncthreads();

    float acc[DIM_][8];
#pragma unroll
    for (int d = 0; d < DIM_; d++)
#pragma unroll
        for (int i = 0; i < 8; i++) acc[d][i] = 0.f;

#pragma unroll
    for (int j = 0; j < NNGB_; j++) {
        int idx = nn[j * NSITES_ + s];
        const float4* p = (const float4*)(InT + (idx << 5) + (q << 3));
        float4 v0 = p[0];
        float4 v1 = p[1];
        float w0 = ws[0 * NNGB_ + j];
        float w1 = ws[1 * NNGB_ + j];
        float w2 = ws[2 * NNGB_ + j];
        float vv[8] = {v0.x, v0.y, v0.z, v0.w, v1.x, v1.y, v1.z, v1.w};
#pragma unroll
        for (int i = 0; i < 8; i++) {
            acc[0][i] += w0 * vv[i];
            acc[1][i] += w1 * vv[i];
            acc[2][i] += w2 * vv[i];
        }
    }

#pragma unroll
    for (int i = 0; i < 8; i++) {
        int b = q * 8 + i;
#pragma unroll
        for (int d = 0; d < DIM_; d++)
            out[(b * DIM_ + d) * NSITES_ + s] = acc[d][i];
    }
}

// ---------------------------------------------------------------------------
// Fallback (tiny ws): direct gather from batch-major In. Slower but correct.
// thread = (b, s)
// ---------------------------------------------------------------------------
__global__ __launch_bounds__(256) void gather_fallback_78486(
    const float* __restrict__ In,
    const int*   __restrict__ nn,
    const float* __restrict__ wm,
    float* __restrict__ out)
{
    const int t = blockIdx.x * 256 + threadIdx.x;   // 0..2097151
    const int s = t & (NSITES_ - 1);
    const int b = t >> 16;
    float a0 = 0.f, a1 = 0.f, a2 = 0.f;
#pragma unroll
    for (int j = 0; j < NNGB_; j++) {
        int idx = nn[j * NSITES_ + s];
        float v = In[b * NSITES_ + idx];
        a0 += wm[0 * NNGB_ + j] * v;
        a1 += wm[1 * NNGB_ + j] * v;
        a2 += wm[2 * NNGB_ + j] * v;
    }
    out[(b * DIM_ + 0) * NSITES_ + s] = a0;
    out[(b * DIM_ + 1) * NSITES_ + s] = a1;
    out[(b * DIM_ + 2) * NSITES_ + s] = a2;
}

extern "C" void kernel_launch(void* const* d_in, const int* in_sizes, int n_in,
                              void* d_out, int out_size, void* d_ws, size_t ws_size,
                              hipStream_t stream)
{
    const float* In     = (const float*)d_in[0];   // (32,1,65536) f32
    const float* wtVC   = (const float*)d_in[1];   // (3,13) f32
    const float* gdiags = (const float*)d_in[2];   // (144,144) f32
    const int*   perms  = (const int*)d_in[3];     // (48,13) i32
    const int*   nn     = (const int*)d_in[4];     // (13,65536) i32
    float* out = (float*)d_out;

    float* wm  = (float*)d_ws;                     // 39 floats (pad to 256)
    float* InT = (float*)d_ws + 256;               // 65536*32 floats = 8 MB

    const size_t need = 256 * sizeof(float) + (size_t)NSITES_ * NB_ * sizeof(float);

    // Wmean (tiny, one block)
    wmean_kernel_78486<<<1, 256, 0, stream>>>(wtVC, gdiags, perms, wm);

    if (ws_size >= need) {
        // Transpose In -> InT (site-major)
        transpose_kernel_78486<<<NSITES_ / 64, 256, 0, stream>>>(In, InT);
        // Main gather-conv
        gather_kernel_78486<<<(NSITES_ * 4) / 256, 256, 0, stream>>>(InT, nn, wm, out);
    } else {
        gather_fallback_78486<<<(NSITES_ * NB_) / 256, 256, 0, stream>>>(In, nn, wm, out);
    }
}

// Round 2
// 96.557 us; speedup vs baseline: 1.0291x; 1.0291x over previous
//
#include <hip/hip_runtime.h>

#define NB_     32
#define NSITES_ 65536
#define NNGB_   13
#define DIM_    3
#define NG_     48
#define GD_     (NG_ * DIM_)   // 144

// ---------------------------------------------------------------------------
// Kernel A (fused):
//   blocks [0, 39):   Wmean entry per block. Wmean[d,j] =
//                     (1/48) sum_g sum_k gdiags[(g*3+d),k] * Wp[k,j],
//                     Wp[k,j] = wtVC[k%3][perms[k/3][j]]
//   blocks [39, ...): transpose In (32,65536) f32 -> InT (65536,32) bf16
// ---------------------------------------------------------------------------
__global__ __launch_bounds__(256) void prep_kernel_78486(
    const float* __restrict__ In,
    const float* __restrict__ wtVC,
    const float* __restrict__ gdiags,
    const int*   __restrict__ perms,
    float*  __restrict__ wm,      // 39 floats
    ushort* __restrict__ InT,     // 65536*32 bf16 (may be null in fallback)
    int nTransBlocks)
{
    const int t = threadIdx.x;
    if ((int)blockIdx.x < DIM_ * NNGB_) {
        const int p = blockIdx.x;
        const int d = p / NNGB_, j = p - NNGB_ * d;
        __shared__ float wpj[GD_];
        __shared__ float red[4];
        if (t < GD_) {
            int g = t / DIM_, dp = t - DIM_ * g;   // k = g*3+dp = t
            wpj[t] = wtVC[dp * NNGB_ + perms[g * NNGB_ + j]];
        }
        __syncthreads();
        float acc = 0.f;
        for (int e = t; e < NG_ * GD_; e += 256) {   // 6912, coalesced over k
            int g = e / GD_;
            int k = e - g * GD_;
            acc += gdiags[(g * DIM_ + d) * GD_ + k] * wpj[k];
        }
#pragma unroll
        for (int off = 32; off > 0; off >>= 1) acc += __shfl_down(acc, off, 64);
        if ((t & 63) == 0) red[t >> 6] = acc;
        __syncthreads();
        if (t == 0) wm[p] = (red[0] + red[1] + red[2] + red[3]) * (1.0f / NG_);
    } else {
        const int tb = blockIdx.x - DIM_ * NNGB_;
        if (tb >= nTransBlocks) return;
        const int s0 = tb * 64;
        __shared__ ushort tile[64][40];   // 80-B rows: 16-B aligned reads
        const int sl = t & 63, bq = t >> 6;
#pragma unroll
        for (int r = 0; r < 8; r++) {
            int b = bq * 8 + r;
            float v = In[b * NSITES_ + s0 + sl];
            unsigned fu = __float_as_uint(v);
            fu = fu + 0x7FFFu + ((fu >> 16) & 1u);   // round-to-nearest-even
            tile[sl][b] = (ushort)(fu >> 16);
        }
        __syncthreads();
        const int site = t >> 2, q = t & 3;          // 64 sites x 4 quads
        uint4 val = *(const uint4*)&tile[site][q * 8];
        *(uint4*)(InT + (size_t)(s0 + site) * NB_ + q * 8) = val;
    }
}

// ---------------------------------------------------------------------------
// Kernel B: gather-conv from bf16 InT (4 MB -> L2-resident per XCD).
// thread = (site, batch-half). 2 lanes/site read the contiguous 64-B row.
// ---------------------------------------------------------------------------
__global__ __launch_bounds__(256) void gather_kernel_78486(
    const ushort* __restrict__ InT,
    const int*    __restrict__ nn,    // (13, 65536)
    const float*  __restrict__ wm,    // 39
    float* __restrict__ out)          // (32, 3, 65536)
{
    const int t = blockIdx.x * 256 + threadIdx.x;   // 0..131071
    const int h = t & 1;                            // batch half
    const int s = t >> 1;                           // site

    __shared__ float ws[DIM_ * NNGB_];
    if (threadIdx.x < DIM_ * NNGB_) ws[threadIdx.x] = wm[threadIdx.x];
    __syncthreads();

    float acc0[16], acc1[16], acc2[16];
#pragma unroll
    for (int i = 0; i < 16; i++) { acc0[i] = 0.f; acc1[i] = 0.f; acc2[i] = 0.f; }

#pragma unroll
    for (int j = 0; j < NNGB_; j++) {
        int idx = nn[j * NSITES_ + s];
        const uint4* p = (const uint4*)(InT + ((size_t)idx << 5) + (h << 4));
        uint4 a = p[0];
        uint4 b = p[1];
        unsigned uu[8] = {a.x, a.y, a.z, a.w, b.x, b.y, b.z, b.w};
        float v[16];
#pragma unroll
        for (int k = 0; k < 8; k++) {
            v[2 * k]     = __uint_as_float(uu[k] << 16);
            v[2 * k + 1] = __uint_as_float(uu[k] & 0xFFFF0000u);
        }
        float w0 = ws[j], w1 = ws[NNGB_ + j], w2 = ws[2 * NNGB_ + j];
#pragma unroll
        for (int i = 0; i < 16; i++) {
            acc0[i] += w0 * v[i];
            acc1[i] += w1 * v[i];
            acc2[i] += w2 * v[i];
        }
    }

#pragma unroll
    for (int i = 0; i < 16; i++) {
        int b = h * 16 + i;
        size_t base = (size_t)b * DIM_ * NSITES_ + s;
        out[base]               = acc0[i];
        out[base + NSITES_]     = acc1[i];
        out[base + 2 * NSITES_] = acc2[i];
    }
}

// ---------------------------------------------------------------------------
// Fallback (tiny ws): direct gather from batch-major In fp32.
// ---------------------------------------------------------------------------
__global__ __launch_bounds__(256) void gather_fallback_78486(
    const float* __restrict__ In,
    const int*   __restrict__ nn,
    const float* __restrict__ wm,
    float* __restrict__ out)
{
    const int t = blockIdx.x * 256 + threadIdx.x;
    const int s = t & (NSITES_ - 1);
    const int b = t >> 16;
    float a0 = 0.f, a1 = 0.f, a2 = 0.f;
#pragma unroll
    for (int j = 0; j < NNGB_; j++) {
        int idx = nn[j * NSITES_ + s];
        float v = In[b * NSITES_ + idx];
        a0 += wm[0 * NNGB_ + j] * v;
        a1 += wm[1 * NNGB_ + j] * v;
        a2 += wm[2 * NNGB_ + j] * v;
    }
    out[(b * DIM_ + 0) * NSITES_ + s] = a0;
    out[(b * DIM_ + 1) * NSITES_ + s] = a1;
    out[(b * DIM_ + 2) * NSITES_ + s] = a2;
}

extern "C" void kernel_launch(void* const* d_in, const int* in_sizes, int n_in,
                              void* d_out, int out_size, void* d_ws, size_t ws_size,
                              hipStream_t stream)
{
    const float* In     = (const float*)d_in[0];   // (32,1,65536) f32
    const float* wtVC   = (const float*)d_in[1];   // (3,13) f32
    const float* gdiags = (const float*)d_in[2];   // (144,144) f32
    const int*   perms  = (const int*)d_in[3];     // (48,13) i32
    const int*   nn     = (const int*)d_in[4];     // (13,65536) i32
    float* out = (float*)d_out;

    float*  wm  = (float*)d_ws;                          // 39 floats
    ushort* InT = (ushort*)((char*)d_ws + 1024);         // 4 MB bf16

    const size_t need = 1024 + (size_t)NSITES_ * NB_ * sizeof(ushort);
    const int nTrans = NSITES_ / 64;                     // 1024

    if (ws_size >= need) {
        prep_kernel_78486<<<DIM_ * NNGB_ + nTrans, 256, 0, stream>>>(
            In, wtVC, gdiags, perms, wm, InT, nTrans);
        gather_kernel_78486<<<(NSITES_ * 2) / 256, 256, 0, stream>>>(
            InT, nn, wm, out);
    } else {
        prep_kernel_78486<<<DIM_ * NNGB_, 256, 0, stream>>>(
            In, wtVC, gdiags, perms, wm, (ushort*)nullptr, 0);
        gather_fallback_78486<<<(NSITES_ * NB_) / 256, 256, 0, stream>>>(
            In, nn, wm, out);
    }
}